// Round 8
// baseline (1485.424 us; speedup 1.0000x reference)
//
#include <hip/hip_runtime.h>

#define NB    256
#define NIN   128
#define DD    256
#define NOUT  32
#define HDIM  64
#define NV    2048          // NOUT*HDIM
#define EPS   1e-8f

typedef __attribute__((ext_vector_type(8))) short short8v;
typedef __attribute__((ext_vector_type(4))) float float4v;

__device__ __forceinline__ unsigned short f2bf(float f) {
    unsigned u = __float_as_uint(f);
    u += 0x7fffu + ((u >> 16) & 1u);
    return (unsigned short)(u >> 16);
}
__device__ __forceinline__ float bf2f(unsigned short h) {
    return __uint_as_float(((unsigned)h) << 16);
}

// ---------------------------------------------------------------------------
// K1: u = squash(x·Wcap + Bcap) -> u_hi/u_lo (bf16 split), ai = ||u||
// ---------------------------------------------------------------------------
__global__ __launch_bounds__(256, 2) void k_u_ai(
    const float* __restrict__ x, const float* __restrict__ Wcap,
    const float* __restrict__ Bcap, unsigned short* __restrict__ u_hi,
    unsigned short* __restrict__ u_lo, float* __restrict__ ai)
{
    const int i  = blockIdx.x;          // 0..127
    const int n0 = blockIdx.y * 64;     // 0,64,128,192
    const int t  = threadIdx.x;

    __shared__ float Wl[128][68];
    __shared__ float xl[64][132];

    const int tn = t >> 4, th = t & 15;
    const int hbase = th * 4;

    float acc[4][4];
    {
        const float4 b = *(const float4*)(Bcap + i * 64 + hbase);
        #pragma unroll
        for (int r = 0; r < 4; ++r) { acc[r][0]=b.x; acc[r][1]=b.y; acc[r][2]=b.z; acc[r][3]=b.w; }
    }

    for (int half = 0; half < 2; ++half) {
        const float4* wsrc = (const float4*)(Wcap + (size_t)i * DD * 64 + (size_t)half * 128 * 64);
        #pragma unroll
        for (int p = 0; p < 8; ++p) {
            int k = t + p * 256;
            float4 v = wsrc[k];
            int d = k >> 4, h4 = (k & 15) * 4;
            *(float4*)&Wl[d][h4] = v;
        }
        #pragma unroll
        for (int p = 0; p < 8; ++p) {
            int k = t + p * 256;
            int row = k >> 5, c4 = (k & 31) * 4;
            float4 v = *(const float4*)(x + ((size_t)(n0 + row) * NIN + i) * DD + half * 128 + c4);
            *(float4*)&xl[row][c4] = v;
        }
        __syncthreads();
        #pragma unroll 4
        for (int d = 0; d < 128; ++d) {
            float a0 = xl[tn*4+0][d], a1 = xl[tn*4+1][d], a2 = xl[tn*4+2][d], a3 = xl[tn*4+3][d];
            float w0 = Wl[d][hbase+0], w1 = Wl[d][hbase+1], w2 = Wl[d][hbase+2], w3 = Wl[d][hbase+3];
            acc[0][0]=fmaf(a0,w0,acc[0][0]); acc[0][1]=fmaf(a0,w1,acc[0][1]); acc[0][2]=fmaf(a0,w2,acc[0][2]); acc[0][3]=fmaf(a0,w3,acc[0][3]);
            acc[1][0]=fmaf(a1,w0,acc[1][0]); acc[1][1]=fmaf(a1,w1,acc[1][1]); acc[1][2]=fmaf(a1,w2,acc[1][2]); acc[1][3]=fmaf(a1,w3,acc[1][3]);
            acc[2][0]=fmaf(a2,w0,acc[2][0]); acc[2][1]=fmaf(a2,w1,acc[2][1]); acc[2][2]=fmaf(a2,w2,acc[2][2]); acc[2][3]=fmaf(a2,w3,acc[2][3]);
            acc[3][0]=fmaf(a3,w0,acc[3][0]); acc[3][1]=fmaf(a3,w1,acc[3][1]); acc[3][2]=fmaf(a3,w2,acc[3][2]); acc[3][3]=fmaf(a3,w3,acc[3][3]);
        }
        __syncthreads();
    }

    #pragma unroll
    for (int r = 0; r < 4; ++r) {
        float s = acc[r][0]*acc[r][0] + acc[r][1]*acc[r][1] + acc[r][2]*acc[r][2] + acc[r][3]*acc[r][3];
        s += __shfl_xor(s, 1); s += __shfl_xor(s, 2); s += __shfl_xor(s, 4); s += __shfl_xor(s, 8);
        float n2 = s, nrm = sqrtf(n2);
        float f = (n2 / (n2 + 1.0f)) / (nrm + EPS);
        int n = n0 + tn * 4 + r;
        float v0 = f*acc[r][0], v1 = f*acc[r][1], v2 = f*acc[r][2], v3 = f*acc[r][3];
        unsigned short ha = f2bf(v0), hb = f2bf(v1), hc = f2bf(v2), hd = f2bf(v3);
        unsigned short la = f2bf(v0 - bf2f(ha)), lb = f2bf(v1 - bf2f(hb));
        unsigned short lc = f2bf(v2 - bf2f(hc)), ld = f2bf(v3 - bf2f(hd));
        size_t eo = ((size_t)n * NIN + i) * HDIM + hbase;
        *(uint2*)(u_hi + eo) = make_uint2((unsigned)ha | ((unsigned)hb << 16), (unsigned)hc | ((unsigned)hd << 16));
        *(uint2*)(u_lo + eo) = make_uint2((unsigned)la | ((unsigned)lb << 16), (unsigned)lc | ((unsigned)ld << 16));
        if (th == 0) ai[(size_t)n * NIN + i] = f * nrm;
    }
}

// ---------------------------------------------------------------------------
// K1b: Wv [io][d][h] f32 -> Wt_hi/Wt_lo [io][h][d] bf16 (transpose + split)
// ---------------------------------------------------------------------------
__global__ __launch_bounds__(256, 4) void k_wconv(
    const float* __restrict__ Wv, unsigned short* __restrict__ Wth,
    unsigned short* __restrict__ Wtl)
{
    const int io = blockIdx.x;
    const int t  = threadIdx.x;
    __shared__ float tile[64][68];

    const float4* src = (const float4*)(Wv + (size_t)io * 4096);
    const int d = t >> 2, hb = (t & 3) * 16;
    #pragma unroll
    for (int q = 0; q < 4; ++q) {
        float4 v = src[t * 4 + q];
        *(float4*)&tile[d][hb + q * 4] = v;
    }
    __syncthreads();
    const int h = t >> 2, d0 = (t & 3) * 16;
    unsigned hp[8], lp[8];
    #pragma unroll
    for (int j = 0; j < 8; ++j) {
        float fa = tile[d0 + 2*j][h], fb = tile[d0 + 2*j + 1][h];
        unsigned short ha = f2bf(fa), hbb = f2bf(fb);
        unsigned short la = f2bf(fa - bf2f(ha)), lb = f2bf(fb - bf2f(hbb));
        hp[j] = (unsigned)ha | ((unsigned)hbb << 16);
        lp[j] = (unsigned)la | ((unsigned)lb << 16);
    }
    size_t eo = (size_t)io * 4096 + (size_t)h * 64 + d0;
    *(uint4*)(Wth + eo)     = make_uint4(hp[0], hp[1], hp[2], hp[3]);
    *(uint4*)(Wth + eo + 8) = make_uint4(hp[4], hp[5], hp[6], hp[7]);
    *(uint4*)(Wtl + eo)     = make_uint4(lp[0], lp[1], lp[2], lp[3]);
    *(uint4*)(Wtl + eo + 8) = make_uint4(lp[4], lp[5], lp[6], lp[7]);
}

// ---------------------------------------------------------------------------
// K2: votes via split-bf16 MFMA -> f16 PERMUTED layout.
// Element (n,i,o,h): g=h>>5, q=(h&31)>>3, c=h&7 stored at (q*64+o*2+g)*8+c
// within the (n,i) slab of 2048 halfs -> wave reads are contiguous 1KB.
// ---------------------------------------------------------------------------
__global__ __launch_bounds__(256, 3) void k_votes(
    const unsigned short* __restrict__ u_hi, const unsigned short* __restrict__ u_lo,
    const unsigned short* __restrict__ Wth, const unsigned short* __restrict__ Wtl,
    const float* __restrict__ Bv, const float* __restrict__ mask,
    _Float16* __restrict__ votes)
{
    const int i   = blockIdx.x;
    const int op  = blockIdx.y;
    const int t   = threadIdx.x;
    const int iob = i * 32 + op * 2;

    __shared__ __align__(16) char lds[49920];
    float* biasl = (float*)(lds + 49152);
    float* msk   = (float*)(lds + 49664);

    {   // stage B once
        const int o = t >> 7, cc = t & 127;
        #pragma unroll
        for (int q = 0; q < 4; ++q) {
            int c = cc + q * 128;
            int h = c >> 3, dby = (c & 7) * 16;
            size_t gb = (size_t)(iob + o) * 8192 + (size_t)c * 16;
            uint4 vh = *(const uint4*)((const char*)Wth + gb);
            uint4 vl = *(const uint4*)((const char*)Wtl + gb);
            int lb = o * 16384 + h * 128 + (dby ^ ((h & 7) << 4));
            *(uint4*)(lds + lb)        = vh;
            *(uint4*)(lds + lb + 8192) = vl;
        }
    }
    if (t < 128) biasl[t] = Bv[(size_t)(iob + (t >> 6)) * 64 + (t & 63)];

    const int w = t >> 6, lane = t & 63;
    const int o_l = w & 1, mi0 = (w >> 1) * 2;
    const int lr = lane & 15, lg = lane >> 4;

    for (int nz = 0; nz < 4; ++nz) {
        const int nbase = nz * 64;
        __syncthreads();
        {   // stage A
            const int n = t >> 2, s = t & 3;
            size_t gb = ((size_t)(nbase + n) * NIN + i) * HDIM * 2;
            #pragma unroll
            for (int p = 0; p < 2; ++p) {
                int dby = s * 32 + p * 16;
                int lb = 32768 + n * 128 + (dby ^ ((n & 7) << 4));
                uint4 vh = *(const uint4*)((const char*)u_hi + gb + dby);
                uint4 vl = *(const uint4*)((const char*)u_lo + gb + dby);
                *(uint4*)(lds + lb)        = vh;
                *(uint4*)(lds + lb + 8192) = vl;
            }
        }
        if (t < 64) msk[t] = mask[(size_t)(nbase + t) * NIN + i];
        __syncthreads();

        float4v acc[2][4];
        #pragma unroll
        for (int a = 0; a < 2; ++a)
            #pragma unroll
            for (int b = 0; b < 4; ++b)
                acc[a][b] = (float4v){0.f, 0.f, 0.f, 0.f};

        #pragma unroll
        for (int ks = 0; ks < 2; ++ks) {
            const int colby = ks * 64 + lg * 16;
            short8v ah[2], al[2], bh[4], bl[4];
            #pragma unroll
            for (int mi = 0; mi < 2; ++mi) {
                int row = (mi0 + mi) * 16 + lr;
                int ob = 32768 + row * 128 + (colby ^ ((row & 7) << 4));
                ah[mi] = *(const short8v*)(lds + ob);
                al[mi] = *(const short8v*)(lds + ob + 8192);
            }
            #pragma unroll
            for (int ni = 0; ni < 4; ++ni) {
                int hrow = ni * 16 + lr;
                int ob = o_l * 16384 + hrow * 128 + (colby ^ ((hrow & 7) << 4));
                bh[ni] = *(const short8v*)(lds + ob);
                bl[ni] = *(const short8v*)(lds + ob + 8192);
            }
            #pragma unroll
            for (int mi = 0; mi < 2; ++mi)
                #pragma unroll
                for (int ni = 0; ni < 4; ++ni) {
                    acc[mi][ni] = __builtin_amdgcn_mfma_f32_16x16x32_bf16(ah[mi], bh[ni], acc[mi][ni], 0, 0, 0);
                    acc[mi][ni] = __builtin_amdgcn_mfma_f32_16x16x32_bf16(al[mi], bh[ni], acc[mi][ni], 0, 0, 0);
                    acc[mi][ni] = __builtin_amdgcn_mfma_f32_16x16x32_bf16(ah[mi], bl[ni], acc[mi][ni], 0, 0, 0);
                }
        }

        #pragma unroll
        for (int mi = 0; mi < 2; ++mi) {
            #pragma unroll
            for (int r = 0; r < 4; ++r) {
                int n_loc = (mi0 + mi) * 16 + lg * 4 + r;
                float mv = msk[n_loc];
                size_t sb = ((size_t)(nbase + n_loc) * NIN + i) * NV;
                #pragma unroll
                for (int ni = 0; ni < 4; ++ni) {
                    int h = ni * 16 + lr;
                    float val = (acc[mi][ni][r] + biasl[o_l * 64 + h]) * mv;
                    int q2 = ((ni & 1) << 1) | (lr >> 3);
                    int off = (q2 * 64 + (op * 2 + o_l) * 2 + (ni >> 1)) * 8 + (lr & 7);
                    votes[sb + off] = (_Float16)val;
                }
            }
        }
    }
}

// ---------------------------------------------------------------------------
// Routing as separate pass kernels.  256-thr blocks, grid (NB, 4 i-chunks).
// Lane (o=lane>>1, g=lane&1); wave handles 8 i.  Per-thread state <= ~115
// floats; partial vj-sums merged via global f32 atomicAdd into vjp_sum.
// Inter-pass barrier = kernel boundary (stream order).
// ---------------------------------------------------------------------------
#define LOADS16(DST, N, I) do {                                              \
    const uint4* _p = (const uint4*)(votes + ((size_t)(N) * NIN + (I)) * NV) + lane; \
    _Pragma("unroll")                                                        \
    for (int _q = 0; _q < 4; ++_q) {                                         \
        uint4 _v = _p[_q * 64];                                              \
        const _Float16* _h = (const _Float16*)&_v;                           \
        _Pragma("unroll")                                                    \
        for (int _c = 0; _c < 8; ++_c) (DST)[_q*8+_c] = (float)_h[_c];       \
    }                                                                        \
} while (0)

__global__ __launch_bounds__(256) void k_p1(
    const _Float16* __restrict__ votes, const float* __restrict__ ai,
    float* __restrict__ vjp_sum)
{
    const int n = blockIdx.x, ic = blockIdx.y;
    const int t = threadIdx.x;
    const int w = t >> 6, lane = t & 63;
    const int o = lane >> 1, g = lane & 1;
    const int ib = ic * 32 + w * 8;

    float vjp[32];
    #pragma unroll
    for (int j = 0; j < 32; ++j) vjp[j] = 0.f;

    for (int k = 0; k < 8; ++k) {
        const int i = ib + k;
        float c = ai[(size_t)n * NIN + i] * (1.0f / 33.0f);
        const uint4* p = (const uint4*)(votes + ((size_t)n * NIN + i) * NV) + lane;
        #pragma unroll
        for (int q = 0; q < 4; ++q) {
            uint4 v = p[q * 64];
            const _Float16* h = (const _Float16*)&v;
            #pragma unroll
            for (int cc = 0; cc < 8; ++cc) vjp[q*8+cc] = fmaf(c, (float)h[cc], vjp[q*8+cc]);
        }
    }
    float* dst = vjp_sum + (size_t)n * NV + o * 64 + g * 32;
    #pragma unroll
    for (int j = 0; j < 32; ++j) atomicAdd(dst + j, vjp[j]);
}

__global__ __launch_bounds__(256) void k_p23(
    const _Float16* __restrict__ votes, const float* __restrict__ ai,
    const float* __restrict__ vj_in, float* __restrict__ bij,
    float* __restrict__ vjp_sum, int final_pass)
{
    const int n = blockIdx.x, ic = blockIdx.y;
    const int t = threadIdx.x;
    const int w = t >> 6, lane = t & 63;
    const int o = lane >> 1, g = lane & 1;
    const int ib = ic * 32 + w * 8;

    float vjr[32];
    {
        const float4* vp = (const float4*)(vj_in + (size_t)n * NV + o * 64 + g * 32);
        #pragma unroll
        for (int q = 0; q < 8; ++q) {
            float4 v = vp[q];
            vjr[q*4+0]=v.x; vjr[q*4+1]=v.y; vjr[q*4+2]=v.z; vjr[q*4+3]=v.w;
        }
    }

    float vjp[32];
    #pragma unroll
    for (int j = 0; j < 32; ++j) vjp[j] = 0.f;

    for (int k = 0; k < 8; ++k) {
        const int i = ib + k;
        float s[32];
        LOADS16(s, n, i);

        float ag = 0.f;
        #pragma unroll
        for (int j = 0; j < 32; ++j) ag = fmaf(s[j], vjr[j], ag);
        ag += __shfl_xor(ag, 1);

        size_t bo = ((size_t)n * NIN + i) * NOUT + o;
        float b = bij[bo] + ag;
        if (!final_pass && g == 0) bij[bo] = b;

        float m = b;
        m = fmaxf(m, __shfl_xor(m, 2));  m = fmaxf(m, __shfl_xor(m, 4));
        m = fmaxf(m, __shfl_xor(m, 8));  m = fmaxf(m, __shfl_xor(m, 16));
        m = fmaxf(m, __shfl_xor(m, 32));
        m = fmaxf(m, 0.f);
        float e = __expf(b - m);
        float es = e;
        es += __shfl_xor(es, 2);  es += __shfl_xor(es, 4);
        es += __shfl_xor(es, 8);  es += __shfl_xor(es, 16);
        es += __shfl_xor(es, 32);
        float den = es + __expf(-m);
        float c = ai[(size_t)n * NIN + i] * e / den;

        #pragma unroll
        for (int j = 0; j < 32; ++j) vjp[j] = fmaf(c, s[j], vjp[j]);
    }

    float* dst = vjp_sum + (size_t)n * NV + o * 64 + g * 32;
    #pragma unroll
    for (int j = 0; j < 32; ++j) atomicAdd(dst + j, vjp[j]);
}

// squash per (n,o) row of 64 h; optionally re-zero vjp_sum for next pass.
__global__ __launch_bounds__(256) void k_sq(
    float* __restrict__ vjp_sum, float* __restrict__ dst, int zero)
{
    const int row  = blockIdx.x * 4 + (threadIdx.x >> 6);   // (n*32+o)
    const int lane = threadIdx.x & 63;
    size_t idx = (size_t)row * 64 + lane;
    float v = vjp_sum[idx];
    float ss = v * v;
    ss += __shfl_xor(ss, 1);  ss += __shfl_xor(ss, 2);  ss += __shfl_xor(ss, 4);
    ss += __shfl_xor(ss, 8);  ss += __shfl_xor(ss, 16); ss += __shfl_xor(ss, 32);
    float nr = sqrtf(ss);
    float f = (ss / (ss + 1.0f)) / (nr + EPS);
    dst[idx] = f * v;
    if (zero) vjp_sum[idx] = 0.f;
}

// ---------------------------------------------------------------------------
extern "C" void kernel_launch(void* const* d_in, const int* in_sizes, int n_in,
                              void* d_out, int out_size, void* d_ws, size_t ws_size,
                              hipStream_t stream)
{
    const float* x    = (const float*)d_in[0];
    const float* mask = (const float*)d_in[1];
    const float* Wcap = (const float*)d_in[2];
    const float* Bcap = (const float*)d_in[3];
    const float* Wv   = (const float*)d_in[4];
    const float* Bv   = (const float*)d_in[5];
    float* out = (float*)d_out;

    char* ws = (char*)d_ws;
    // u_hi/u_lo occupy [0, 8 MB); dead after k_votes -> reused for vj/vjp/bij.
    unsigned short* u_hi = (unsigned short*)ws;              //  4,194,304
    unsigned short* u_lo = (unsigned short*)(ws + 4194304);  //  4,194,304
    float*          ai   = (float*)(ws + 8388608);           //    131,072
    unsigned short* Wth  = (unsigned short*)(ws + 8519680);  // 33,554,432
    unsigned short* Wtl  = (unsigned short*)(ws + 42074112); // 33,554,432
    _Float16*       votes= (_Float16*)(ws + 75628544);       // 134,217,728

    float* vj      = (float*)ws;                 // 2 MB  (over dead u_hi)
    float* vjp_sum = (float*)(ws + 2097152);     // 2 MB  (over dead u_hi)
    float* bij     = (float*)(ws + 4194304);     // 4 MB  (over dead u_lo)

    k_u_ai<<<dim3(NIN, 4), 256, 0, stream>>>(x, Wcap, Bcap, u_hi, u_lo, ai);
    k_wconv<<<NIN * NOUT, 256, 0, stream>>>(Wv, Wth, Wtl);
    k_votes<<<dim3(NIN, 16), 256, 0, stream>>>(u_hi, u_lo, Wth, Wtl, Bv, mask, votes);

    // u region dead now; init routing state (stream-ordered after k_votes).
    hipMemsetAsync(vjp_sum, 0, (size_t)NB * NV * 4, stream);
    hipMemsetAsync(bij,     0, (size_t)NB * NIN * NOUT * 4, stream);

    dim3 gp(NB, 4);
    k_p1 <<<gp, 256, 0, stream>>>(votes, ai, vjp_sum);
    k_sq <<<(NB * NOUT) / 4, 256, 0, stream>>>(vjp_sum, vj, 1);
    k_p23<<<gp, 256, 0, stream>>>(votes, ai, vj, bij, vjp_sum, 0);
    k_sq <<<(NB * NOUT) / 4, 256, 0, stream>>>(vjp_sum, vj, 1);
    k_p23<<<gp, 256, 0, stream>>>(votes, ai, vj, bij, vjp_sum, 1);
    k_sq <<<(NB * NOUT) / 4, 256, 0, stream>>>(vjp_sum, out, 0);
}